// Round 9
// baseline (578.684 us; speedup 1.0000x reference)
//
#include <hip/hip_runtime.h>

// SOM vector-quantizer fused kernel for MI355X (gfx950).
// Outputs (flat in d_out): [0] loss scalar, [1 .. 8388608] quantized_st
// in [B,C,D,H,W] layout, [8388609 ..] one-hot encodings [N,256].
//
// N = 262144 voxels, EMB_D = 32, K = 256 (16x16 SOM grid).
//
// R8 -> R9 (DIAGNOSTIC round):
//  * The distance scan runs SCAN_REPS=3 times, with asm register-opacity
//    on xv[] between reps so the compiler cannot CSE the repeats. Each
//    rep re-initializes best/bidx and recomputes the identical result
//    from identical inputs -> bit-exact outputs preserved (absmax 0.0),
//    but the scan's cost is paid 3x.
//  * Purpose: (1) push som_main's duration above the harness's ~15
//    poison-fill dispatches (~195-218us) so it FINALLY appears in the
//    top-5 counter table -- 8 rounds in, we have never seen its
//    VALUBusy/Occupancy/FETCH/WRITE; (2) dur delta vs R7/R8 directly
//    measures the scan's marginal cost (delta = 2x scan). W (8 KB) and
//    wsql (1 KB) cannot be register-cached across reps, so operand
//    delivery is re-paid each rep.
//  * Everything else is byte-identical to R8 (pre-zeroed enc + single
//    1.0 store, wsql-from-LDS, AS4 s_load scan, slot atomics).

#define SOM_K      256
#define EMB_D      32
#define WPAD       36             // LDS row stride (floats): 16B-aligned rows
#define N_VOX      262144
#define SPATIAL    32768          // 32*32*32 per batch
#define OUT_ELEMS  8388608        // 8*32*32768
#define COMMIT_DEN 8388608.0f
#define NSLOT      256            // loss accumulator slots (64B apart)
#define SCAN_REPS  3              // DIAGNOSTIC: 3x scan for counters + ablation

#define CONST_AS __attribute__((address_space(4)))

// ---------------------------------------------------------------------------
// prep: zero the slot accumulators (ws is poisoned to 0xAA every launch).
// ---------------------------------------------------------------------------
__global__ __launch_bounds__(256) void som_prep_kernel(float* __restrict__ ws) {
  float4* p = (float4*)ws;               // 256 slots * 16 floats = 1024 float4
  int t = threadIdx.x;
#pragma unroll
  for (int i = 0; i < 4; ++i) p[i * 256 + t] = make_float4(0.f, 0.f, 0.f, 0.f);
}

// ---------------------------------------------------------------------------
// main fused kernel: 1024 blocks x 256 threads, one thread per voxel.
// ---------------------------------------------------------------------------
__global__ __launch_bounds__(256, 4) void som_main_kernel(
    const float* __restrict__ x,     // [8,32,32,32,32]
    const float* __restrict__ w,     // [256,32]
    float* __restrict__ slots,       // ws: NSLOT x 16 floats
    float* __restrict__ out,         // d_out+1, [8,32,32768]
    float* __restrict__ enc) {       // d_out+1+OUT_ELEMS, [N,256]
  __shared__ __align__(16) float wl[SOM_K * WPAD];
  __shared__ float wsql[SOM_K];      // ||W_k||^2

  const int t = threadIdx.x;
  const CONST_AS float* wcp = (const CONST_AS float*)(unsigned long long)w;

  // Voxel loads first (needed soonest: xsq before the scan).
  const int n    = blockIdx.x * 256 + t;
  const int base = (n >> 15) * (EMB_D * SPATIAL) + (n & (SPATIAL - 1));
  float xv[EMB_D];
#pragma unroll
  for (int c = 0; c < EMB_D; ++c) xv[c] = x[base + c * SPATIAL];

  // Stage W -> LDS (coalesced read, padded scatter write).
#pragma unroll
  for (int i = 0; i < 32; ++i) {
    int e = i * 256 + t;             // 0..8191
    int r = e >> 5, c = e & 31;
    wl[r * WPAD + c] = w[e];
  }

  // Pre-zero this block's enc region (65536 floats, base == 1 mod 4).
  // Fire-and-forget: drains on the VMEM pipe underneath the scan.
  {
    float* rb = enc + (size_t)blockIdx.x * (SOM_K * 256);
    float4* rb4 = (float4*)(rb + 3);                       // 16B-aligned
    const float4 z4 = make_float4(0.f, 0.f, 0.f, 0.f);
#pragma unroll
    for (int i = 0; i < 64; ++i) {
      int idx = i * 256 + t;
      if (idx < 16383) rb4[idx] = z4;
    }
    if (t == 0) { rb[0] = 0.f; rb[1] = 0.f; rb[2] = 0.f; rb[65535] = 0.f; }
  }
  __syncthreads();

  // ||W_t||^2 from the LDS copy -- same sequential fmaf order as R1..R8.
  {
    const float4* row = (const float4*)(wl + t * WPAD);
    float s = 0.0f;
#pragma unroll
    for (int j = 0; j < 8; ++j) {
      float4 q = row[j];
      s = fmaf(q.x, q.x, s);
      s = fmaf(q.y, q.y, s);
      s = fmaf(q.z, q.z, s);
      s = fmaf(q.w, q.w, s);
    }
    wsql[t] = s;
  }

  float xsq = 0.0f;
#pragma unroll
  for (int c = 0; c < EMB_D; ++c) xsq = fmaf(xv[c], xv[c], xsq);
  __syncthreads();

  // Distance scan, repeated SCAN_REPS times (diagnostic). Each rep is
  // bit-identical; asm opacity on xv[] prevents CSE across reps. Inner
  // arithmetic order unchanged from R1..R8 (absmax 0.0).
  float best = 3.402823466e38f;
  int   bidx = 0;
#pragma unroll 1
  for (int rep = 0; rep < SCAN_REPS; ++rep) {
#pragma unroll
    for (int j = 0; j < EMB_D; ++j) asm volatile("" : "+v"(xv[j]));
    best = 3.402823466e38f;
    bidx = 0;
#pragma unroll 2
    for (int k = 0; k < SOM_K; ++k) {
      const CONST_AS float* wr = wcp + (k << 5);
      float dot = 0.0f;
#pragma unroll
      for (int j = 0; j < EMB_D; ++j) dot = fmaf(wr[j], xv[j], dot);
      float d = (xsq + wsql[k]) - 2.0f * dot;   // same rounding order as ref
      if (d < best) { best = d; bidx = k; }
    }
  }

  // Zero-stores retired long ago; seal same-address ordering, then write
  // the single 1.0 of this voxel's one-hot row.
  asm volatile("s_waitcnt vmcnt(0)" ::: "memory");
  enc[(size_t)n * SOM_K + bidx] = 1.0f;

  // Quantized output + commitment-loss partial (gather row bidx from LDS).
  float commit = 0.0f;
  {
    const float4* qrow = (const float4*)(wl + bidx * WPAD);
#pragma unroll
    for (int j = 0; j < 8; ++j) {
      float4 q = qrow[j];
      float qq[4] = { q.x, q.y, q.z, q.w };
#pragma unroll
      for (int u = 0; u < 4; ++u) {
        int c = 4 * j + u;
        out[base + c * SPATIAL] = qq[u];     // coalesced dword store
        float df = qq[u] - xv[c];
        commit = fmaf(df, df, commit);
      }
    }
  }

  // SOM loss: dist to BMU + its up/down/left/right grid neighbors.
  float som = best;
  float cnt = 1.0f;
  {
    const int h   = bidx >> 4;
    const int wc2 = bidx & 15;
    const int   cand[4]  = { bidx - 16, bidx + 16, bidx - 1, bidx + 1 };
    const float valid[4] = { h > 0 ? 1.f : 0.f,  h < 15 ? 1.f : 0.f,
                             wc2 > 0 ? 1.f : 0.f, wc2 < 15 ? 1.f : 0.f };
#pragma unroll
    for (int j = 0; j < 4; ++j) {
      int nk = valid[j] != 0.0f ? cand[j] : bidx;   // clamp (masked anyway)
      const float4* nrow = (const float4*)(wl + nk * WPAD);
      float dot = 0.0f;
#pragma unroll
      for (int jj = 0; jj < 8; ++jj) {
        float4 q = nrow[jj];
        dot = fmaf(q.x, xv[4 * jj + 0], dot);
        dot = fmaf(q.y, xv[4 * jj + 1], dot);
        dot = fmaf(q.z, xv[4 * jj + 2], dot);
        dot = fmaf(q.w, xv[4 * jj + 3], dot);
      }
      float d = (xsq + wsql[nk]) - 2.0f * dot;
      som = fmaf(valid[j], d, som);
      cnt += valid[j];
    }
  }

  // Wave reduction -> 3 atomics per wave into this block's slot.
  for (int off = 32; off > 0; off >>= 1) {
    commit += __shfl_down(commit, off, 64);
    som    += __shfl_down(som,    off, 64);
    cnt    += __shfl_down(cnt,    off, 64);
  }
  if ((t & 63) == 0) {
    float* sp = slots + (size_t)(blockIdx.x & (NSLOT - 1)) * 16;
    atomicAdd(sp + 0, commit);
    atomicAdd(sp + 1, som);
    atomicAdd(sp + 2, cnt);
  }
}

// ---------------------------------------------------------------------------
// final: reduce the 256 slots with one wave.
// ---------------------------------------------------------------------------
__global__ __launch_bounds__(64) void som_final_kernel(
    const float* __restrict__ slots, float* __restrict__ loss) {
  const int t = threadIdx.x;           // one wave
  float commit = 0.f, som = 0.f, cnt = 0.f;
#pragma unroll
  for (int i = 0; i < 4; ++i) {
    const float* sp = slots + (size_t)(i * 64 + t) * 16;
    commit += sp[0]; som += sp[1]; cnt += sp[2];
  }
  for (int off = 32; off > 0; off >>= 1) {
    commit += __shfl_down(commit, off, 64);
    som    += __shfl_down(som,    off, 64);
    cnt    += __shfl_down(cnt,    off, 64);
  }
  if (t == 0) loss[0] = 6.0f * (commit / COMMIT_DEN) + som / cnt;
}

extern "C" void kernel_launch(void* const* d_in, const int* in_sizes, int n_in,
                              void* d_out, int out_size, void* d_ws, size_t ws_size,
                              hipStream_t stream) {
  const float* x = (const float*)d_in[0];   // [8,32,32,32,32]
  const float* w = (const float*)d_in[1];   // [256,32]
  float* ws  = (float*)d_ws;                // NSLOT x 16 float slots
  float* o   = (float*)d_out;               // [0] loss, then out, then enc

  som_prep_kernel<<<1, 256, 0, stream>>>(ws);
  som_main_kernel<<<N_VOX / 256, 256, 0, stream>>>(
      x, w, ws, o + 1, o + 1 + OUT_ELEMS);
  som_final_kernel<<<1, 64, 0, stream>>>(ws, o);
}

// Round 12
// 406.290 us; speedup vs baseline: 1.4243x; 1.4243x over previous
//
#include <hip/hip_runtime.h>

// SOM vector-quantizer fused kernel for MI355X (gfx950).
// Outputs (flat in d_out): [0] loss scalar, [1 .. 8388608] quantized_st
// in [B,C,D,H,W] layout, [8388609 ..] one-hot encodings [N,256].
//
// N = 262144 voxels, EMB_D = 32, K = 256 (16x16 SOM grid).
//
// R10 (third submit; rounds 10-11 broker timeouts, never measured):
//  * R9 diagnostic: scan = 76us/rep, main@1x = 160us, VALUBusy 68%,
//    WRITE 310MB @ ~1TB/s (writes have headroom). Scan left untouched.
//  * THE FIX: enc pre-zero moved AFTER the last __syncthreads. On gfx950
//    __syncthreads emits s_waitcnt vmcnt(0), so R8's pre-barrier zeros
//    were fully drained by the barrier -- the intended overlap with the
//    scan never happened. Now the 268 MB zero stream is issued right
//    before the scan with no intervening barrier: it drains on the VMEM
//    pipe underneath 76us of VALU work.
//  * Race control: zeroing is WAVE-PRIVATE (each wave zeroes exactly the
//    64 one-hot rows its own lanes later write). The per-wave
//    s_waitcnt vmcnt(0) before the 1.0 store orders same-wave same-address
//    stores; no other wave touches those rows.
//  * Zero float-arithmetic changes: scan/wsql/commit/som/atomics are
//    byte-identical to R9@1x -> absmax 0.0 structurally guaranteed.

#define SOM_K      256
#define EMB_D      32
#define WPAD       36             // LDS row stride (floats): 16B-aligned rows
#define N_VOX      262144
#define SPATIAL    32768          // 32*32*32 per batch
#define OUT_ELEMS  8388608        // 8*32*32768
#define COMMIT_DEN 8388608.0f
#define NSLOT      256            // loss accumulator slots (64B apart)

#define CONST_AS __attribute__((address_space(4)))

// ---------------------------------------------------------------------------
// prep: zero the slot accumulators (ws is poisoned to 0xAA every launch).
// ---------------------------------------------------------------------------
__global__ __launch_bounds__(256) void som_prep_kernel(float* __restrict__ ws) {
  float4* p = (float4*)ws;               // 256 slots * 16 floats = 1024 float4
  int t = threadIdx.x;
#pragma unroll
  for (int i = 0; i < 4; ++i) p[i * 256 + t] = make_float4(0.f, 0.f, 0.f, 0.f);
}

// ---------------------------------------------------------------------------
// main fused kernel: 1024 blocks x 256 threads, one thread per voxel.
// ---------------------------------------------------------------------------
__global__ __launch_bounds__(256, 4) void som_main_kernel(
    const float* __restrict__ x,     // [8,32,32,32,32]
    const float* __restrict__ w,     // [256,32]
    float* __restrict__ slots,       // ws: NSLOT x 16 floats
    float* __restrict__ out,         // d_out+1, [8,32,32768]
    float* __restrict__ enc) {       // d_out+1+OUT_ELEMS, [N,256]
  __shared__ __align__(16) float wl[SOM_K * WPAD];
  __shared__ float wsql[SOM_K];      // ||W_k||^2

  const int t = threadIdx.x;
  const CONST_AS float* wcp = (const CONST_AS float*)(unsigned long long)w;

  // Voxel loads first (needed soonest: xsq before the scan).
  const int n    = blockIdx.x * 256 + t;
  const int base = (n >> 15) * (EMB_D * SPATIAL) + (n & (SPATIAL - 1));
  float xv[EMB_D];
#pragma unroll
  for (int c = 0; c < EMB_D; ++c) xv[c] = x[base + c * SPATIAL];

  // Stage W -> LDS (coalesced read, padded scatter write).
#pragma unroll
  for (int i = 0; i < 32; ++i) {
    int e = i * 256 + t;             // 0..8191
    int r = e >> 5, c = e & 31;
    wl[r * WPAD + c] = w[e];
  }
  __syncthreads();   // wl ready (this barrier's vmcnt drain is cheap: x+w reads)

  // ||W_t||^2 from the LDS copy -- same sequential fmaf order as R1..R9.
  {
    const float4* row = (const float4*)(wl + t * WPAD);
    float s = 0.0f;
#pragma unroll
    for (int j = 0; j < 8; ++j) {
      float4 q = row[j];
      s = fmaf(q.x, q.x, s);
      s = fmaf(q.y, q.y, s);
      s = fmaf(q.z, q.z, s);
      s = fmaf(q.w, q.w, s);
    }
    wsql[t] = s;
  }

  float xsq = 0.0f;
#pragma unroll
  for (int c = 0; c < EMB_D; ++c) xsq = fmaf(xv[c], xv[c], xsq);
  __syncthreads();   // wsql ready. LAST barrier in the kernel.

  // Wave-private enc pre-zero, issued AFTER the last barrier so the 268 MB
  // store stream drains underneath the scan (no barrier will force a
  // vmcnt(0) drain before the stores have had 76us to retire).
  // Wave w owns voxels [blk*256 + w*64, +64) -> 16384 floats starting at
  // enc-offset (blk*256+w*64)*256, which is == 1 mod 4 floats (enc base
  // is 1 mod 4, offset is a multiple of 16384). Lead 3 + 4095 float4 +
  // tail 1 keeps every vector store 16B-aligned.
  {
    const int lane = t & 63, wave = t >> 6;
    float* rb = enc + (size_t)(blockIdx.x * 256 + wave * 64) * SOM_K;
    float4* rb4 = (float4*)(rb + 3);
    const float4 z4 = make_float4(0.f, 0.f, 0.f, 0.f);
    for (int r = 0; r < 63; ++r) rb4[r * 64 + lane] = z4;  // idx <= 4031
    if (lane < 63) rb4[4032 + lane] = z4;                  // idx 4032..4094
    if (lane == 0)       { rb[0] = 0.f; rb[1] = 0.f; rb[2] = 0.f; }
    else if (lane == 63) { rb[16383] = 0.f; }
  }

  // Distance scan over all 256 codebook rows (unchanged from R9 @ 1 rep).
  // k wave-uniform + AS4 -> s_load delivery; sequential fmaf order kept
  // (absmax 0.0). The zero stores retire underneath this loop.
  float best = 3.402823466e38f;
  int   bidx = 0;
#pragma unroll 2
  for (int k = 0; k < SOM_K; ++k) {
    const CONST_AS float* wr = wcp + (k << 5);
    float dot = 0.0f;
#pragma unroll
    for (int j = 0; j < EMB_D; ++j) dot = fmaf(wr[j], xv[j], dot);
    float d = (xsq + wsql[k]) - 2.0f * dot;   // same rounding order as ref
    if (d < best) { best = d; bidx = k; }
  }

  // This wave's zero stores have retired under the scan; seal the
  // same-address ordering, then write the single 1.0 of each voxel's row.
  asm volatile("s_waitcnt vmcnt(0)" ::: "memory");
  enc[(size_t)n * SOM_K + bidx] = 1.0f;

  // Quantized output + commitment-loss partial (gather row bidx from LDS).
  float commit = 0.0f;
  {
    const float4* qrow = (const float4*)(wl + bidx * WPAD);
#pragma unroll
    for (int j = 0; j < 8; ++j) {
      float4 q = qrow[j];
      float qq[4] = { q.x, q.y, q.z, q.w };
#pragma unroll
      for (int u = 0; u < 4; ++u) {
        int c = 4 * j + u;
        out[base + c * SPATIAL] = qq[u];     // coalesced dword store
        float df = qq[u] - xv[c];
        commit = fmaf(df, df, commit);
      }
    }
  }

  // SOM loss: dist to BMU + its up/down/left/right grid neighbors.
  float som = best;
  float cnt = 1.0f;
  {
    const int h   = bidx >> 4;
    const int wc2 = bidx & 15;
    const int   cand[4]  = { bidx - 16, bidx + 16, bidx - 1, bidx + 1 };
    const float valid[4] = { h > 0 ? 1.f : 0.f,  h < 15 ? 1.f : 0.f,
                             wc2 > 0 ? 1.f : 0.f, wc2 < 15 ? 1.f : 0.f };
#pragma unroll
    for (int j = 0; j < 4; ++j) {
      int nk = valid[j] != 0.0f ? cand[j] : bidx;   // clamp (masked anyway)
      const float4* nrow = (const float4*)(wl + nk * WPAD);
      float dot = 0.0f;
#pragma unroll
      for (int jj = 0; jj < 8; ++jj) {
        float4 q = nrow[jj];
        dot = fmaf(q.x, xv[4 * jj + 0], dot);
        dot = fmaf(q.y, xv[4 * jj + 1], dot);
        dot = fmaf(q.z, xv[4 * jj + 2], dot);
        dot = fmaf(q.w, xv[4 * jj + 3], dot);
      }
      float d = (xsq + wsql[nk]) - 2.0f * dot;
      som = fmaf(valid[j], d, som);
      cnt += valid[j];
    }
  }

  // Wave reduction -> 3 atomics per wave into this block's slot.
  for (int off = 32; off > 0; off >>= 1) {
    commit += __shfl_down(commit, off, 64);
    som    += __shfl_down(som,    off, 64);
    cnt    += __shfl_down(cnt,    off, 64);
  }
  if ((t & 63) == 0) {
    float* sp = slots + (size_t)(blockIdx.x & (NSLOT - 1)) * 16;
    atomicAdd(sp + 0, commit);
    atomicAdd(sp + 1, som);
    atomicAdd(sp + 2, cnt);
  }
}

// ---------------------------------------------------------------------------
// final: reduce the 256 slots with one wave.
// ---------------------------------------------------------------------------
__global__ __launch_bounds__(64) void som_final_kernel(
    const float* __restrict__ slots, float* __restrict__ loss) {
  const int t = threadIdx.x;           // one wave
  float commit = 0.f, som = 0.f, cnt = 0.f;
#pragma unroll
  for (int i = 0; i < 4; ++i) {
    const float* sp = slots + (size_t)(i * 64 + t) * 16;
    commit += sp[0]; som += sp[1]; cnt += sp[2];
  }
  for (int off = 32; off > 0; off >>= 1) {
    commit += __shfl_down(commit, off, 64);
    som    += __shfl_down(som,    off, 64);
    cnt    += __shfl_down(cnt,    off, 64);
  }
  if (t == 0) loss[0] = 6.0f * (commit / COMMIT_DEN) + som / cnt;
}

extern "C" void kernel_launch(void* const* d_in, const int* in_sizes, int n_in,
                              void* d_out, int out_size, void* d_ws, size_t ws_size,
                              hipStream_t stream) {
  const float* x = (const float*)d_in[0];   // [8,32,32,32,32]
  const float* w = (const float*)d_in[1];   // [256,32]
  float* ws  = (float*)d_ws;                // NSLOT x 16 float slots
  float* o   = (float*)d_out;               // [0] loss, then out, then enc

  som_prep_kernel<<<1, 256, 0, stream>>>(ws);
  som_main_kernel<<<N_VOX / 256, 256, 0, stream>>>(
      x, w, ws, o + 1, o + 1 + OUT_ELEMS);
  som_final_kernel<<<1, 64, 0, stream>>>(ws, o);
}

// Round 15
// 402.735 us; speedup vs baseline: 1.4369x; 1.0088x over previous
//
#include <hip/hip_runtime.h>

// SOM vector-quantizer fused kernel for MI355X (gfx950).
// Outputs (flat in d_out): [0] loss scalar, [1 .. 8388608] quantized_st
// in [B,C,D,H,W] layout, [8388609 ..] one-hot encodings [N,256].
//
// N = 262144 voxels, EMB_D = 32, K = 256 (16x16 SOM grid).
//
// R11 (third submit; rounds 13-14 infra failures, never measured):
//  * R10 (enc zeros issued post-barrier, wave-private) measured -19us
//    same-container vs R8 -> keep. Normalized best: ~362us.
//  * THE CHANGE: distance scan unrolled 4x over k -- four INDEPENDENT
//    32-deep fmaf chains per thread. R9 measured scan=76us vs ~32us
//    pure-issue floor with VALUBusy 68% @ Occupancy 34% (grid-capped
//    ~2.7 waves/SIMD): latency-bound dependent-chain issue gaps. 4
//    chains/thread quadruples ILP without adding waves.
//  * wsql read as one wave-uniform float4 per 4 rows (64 ds_read_b128
//    instead of 256 ds_read_b32). Same values, same use order.
//  * Per-k arithmetic BIT-IDENTICAL: sequential fmaf j=0..31 per row,
//    d=(xsq+wsql[k])-2*dot, compares applied in ascending-k order with
//    strict < (ties keep lowest k, exactly as the sequential loop).
//    absmax 0.0 structurally guaranteed.

#define SOM_K      256
#define EMB_D      32
#define WPAD       36             // LDS row stride (floats): 16B-aligned rows
#define N_VOX      262144
#define SPATIAL    32768          // 32*32*32 per batch
#define OUT_ELEMS  8388608        // 8*32*32768
#define COMMIT_DEN 8388608.0f
#define NSLOT      256            // loss accumulator slots (64B apart)

#define CONST_AS __attribute__((address_space(4)))

// ---------------------------------------------------------------------------
// prep: zero the slot accumulators (ws is poisoned to 0xAA every launch).
// ---------------------------------------------------------------------------
__global__ __launch_bounds__(256) void som_prep_kernel(float* __restrict__ ws) {
  float4* p = (float4*)ws;               // 256 slots * 16 floats = 1024 float4
  int t = threadIdx.x;
#pragma unroll
  for (int i = 0; i < 4; ++i) p[i * 256 + t] = make_float4(0.f, 0.f, 0.f, 0.f);
}

// ---------------------------------------------------------------------------
// main fused kernel: 1024 blocks x 256 threads, one thread per voxel.
// ---------------------------------------------------------------------------
__global__ __launch_bounds__(256, 4) void som_main_kernel(
    const float* __restrict__ x,     // [8,32,32,32,32]
    const float* __restrict__ w,     // [256,32]
    float* __restrict__ slots,       // ws: NSLOT x 16 floats
    float* __restrict__ out,         // d_out+1, [8,32,32768]
    float* __restrict__ enc) {       // d_out+1+OUT_ELEMS, [N,256]
  __shared__ __align__(16) float wl[SOM_K * WPAD];
  __shared__ __align__(16) float wsql[SOM_K];   // ||W_k||^2

  const int t = threadIdx.x;
  const CONST_AS float* wcp = (const CONST_AS float*)(unsigned long long)w;

  // Voxel loads first (needed soonest: xsq before the scan).
  const int n    = blockIdx.x * 256 + t;
  const int base = (n >> 15) * (EMB_D * SPATIAL) + (n & (SPATIAL - 1));
  float xv[EMB_D];
#pragma unroll
  for (int c = 0; c < EMB_D; ++c) xv[c] = x[base + c * SPATIAL];

  // Stage W -> LDS (coalesced read, padded scatter write).
#pragma unroll
  for (int i = 0; i < 32; ++i) {
    int e = i * 256 + t;             // 0..8191
    int r = e >> 5, c = e & 31;
    wl[r * WPAD + c] = w[e];
  }
  __syncthreads();   // wl ready (vmcnt drain here is cheap: x+w reads only)

  // ||W_t||^2 from the LDS copy -- same sequential fmaf order as R1..R10.
  {
    const float4* row = (const float4*)(wl + t * WPAD);
    float s = 0.0f;
#pragma unroll
    for (int j = 0; j < 8; ++j) {
      float4 q = row[j];
      s = fmaf(q.x, q.x, s);
      s = fmaf(q.y, q.y, s);
      s = fmaf(q.z, q.z, s);
      s = fmaf(q.w, q.w, s);
    }
    wsql[t] = s;
  }

  float xsq = 0.0f;
#pragma unroll
  for (int c = 0; c < EMB_D; ++c) xsq = fmaf(xv[c], xv[c], xsq);
  __syncthreads();   // wsql ready. LAST barrier in the kernel.

  // Wave-private enc pre-zero, issued AFTER the last barrier so the 268 MB
  // store stream drains on the VMEM pipe underneath the scan (R10 win).
  {
    const int lane = t & 63, wave = t >> 6;
    float* rb = enc + (size_t)(blockIdx.x * 256 + wave * 64) * SOM_K;
    float4* rb4 = (float4*)(rb + 3);
    const float4 z4 = make_float4(0.f, 0.f, 0.f, 0.f);
    for (int r = 0; r < 63; ++r) rb4[r * 64 + lane] = z4;  // idx <= 4031
    if (lane < 63) rb4[4032 + lane] = z4;                  // idx 4032..4094
    if (lane == 0)       { rb[0] = 0.f; rb[1] = 0.f; rb[2] = 0.f; }
    else if (lane == 63) { rb[16383] = 0.f; }
  }

  // Distance scan, 4 rows per iteration: 4 INDEPENDENT fmaf chains (ILP=4).
  // Each row's dot uses the same sequential fmaf j=0..31 as before; the
  // 4 compares run in ascending-k order with strict < -> argmin identical
  // (incl. exact ties). wsql fetched as one wave-uniform float4 per group.
  float best = 3.402823466e38f;
  int   bidx = 0;
  const float4* wsq4 = (const float4*)wsql;
#pragma unroll 1
  for (int k = 0; k < SOM_K; k += 4) {
    const CONST_AS float* r0 = wcp + (k << 5);
    const CONST_AS float* r1 = r0 + 32;
    const CONST_AS float* r2 = r0 + 64;
    const CONST_AS float* r3 = r0 + 96;
    float d0 = 0.0f, d1 = 0.0f, d2 = 0.0f, d3 = 0.0f;
#pragma unroll
    for (int j = 0; j < EMB_D; ++j) {
      const float xj = xv[j];
      d0 = fmaf(r0[j], xj, d0);
      d1 = fmaf(r1[j], xj, d1);
      d2 = fmaf(r2[j], xj, d2);
      d3 = fmaf(r3[j], xj, d3);
    }
    const float4 ws4 = wsq4[k >> 2];
    const float e0 = (xsq + ws4.x) - 2.0f * d0;   // same rounding order
    const float e1 = (xsq + ws4.y) - 2.0f * d1;
    const float e2 = (xsq + ws4.z) - 2.0f * d2;
    const float e3 = (xsq + ws4.w) - 2.0f * d3;
    if (e0 < best) { best = e0; bidx = k;     }
    if (e1 < best) { best = e1; bidx = k + 1; }
    if (e2 < best) { best = e2; bidx = k + 2; }
    if (e3 < best) { best = e3; bidx = k + 3; }
  }

  // This wave's zero stores retired under the scan; seal the same-address
  // ordering, then write the single 1.0 of each voxel's one-hot row.
  asm volatile("s_waitcnt vmcnt(0)" ::: "memory");
  enc[(size_t)n * SOM_K + bidx] = 1.0f;

  // Quantized output + commitment-loss partial (gather row bidx from LDS).
  float commit = 0.0f;
  {
    const float4* qrow = (const float4*)(wl + bidx * WPAD);
#pragma unroll
    for (int j = 0; j < 8; ++j) {
      float4 q = qrow[j];
      float qq[4] = { q.x, q.y, q.z, q.w };
#pragma unroll
      for (int u = 0; u < 4; ++u) {
        int c = 4 * j + u;
        out[base + c * SPATIAL] = qq[u];     // coalesced dword store
        float df = qq[u] - xv[c];
        commit = fmaf(df, df, commit);
      }
    }
  }

  // SOM loss: dist to BMU + its up/down/left/right grid neighbors.
  float som = best;
  float cnt = 1.0f;
  {
    const int h   = bidx >> 4;
    const int wc2 = bidx & 15;
    const int   cand[4]  = { bidx - 16, bidx + 16, bidx - 1, bidx + 1 };
    const float valid[4] = { h > 0 ? 1.f : 0.f,  h < 15 ? 1.f : 0.f,
                             wc2 > 0 ? 1.f : 0.f, wc2 < 15 ? 1.f : 0.f };
#pragma unroll
    for (int j = 0; j < 4; ++j) {
      int nk = valid[j] != 0.0f ? cand[j] : bidx;   // clamp (masked anyway)
      const float4* nrow = (const float4*)(wl + nk * WPAD);
      float dot = 0.0f;
#pragma unroll
      for (int jj = 0; jj < 8; ++jj) {
        float4 q = nrow[jj];
        dot = fmaf(q.x, xv[4 * jj + 0], dot);
        dot = fmaf(q.y, xv[4 * jj + 1], dot);
        dot = fmaf(q.z, xv[4 * jj + 2], dot);
        dot = fmaf(q.w, xv[4 * jj + 3], dot);
      }
      float d = (xsq + wsql[nk]) - 2.0f * dot;
      som = fmaf(valid[j], d, som);
      cnt += valid[j];
    }
  }

  // Wave reduction -> 3 atomics per wave into this block's slot.
  for (int off = 32; off > 0; off >>= 1) {
    commit += __shfl_down(commit, off, 64);
    som    += __shfl_down(som,    off, 64);
    cnt    += __shfl_down(cnt,    off, 64);
  }
  if ((t & 63) == 0) {
    float* sp = slots + (size_t)(blockIdx.x & (NSLOT - 1)) * 16;
    atomicAdd(sp + 0, commit);
    atomicAdd(sp + 1, som);
    atomicAdd(sp + 2, cnt);
  }
}

// ---------------------------------------------------------------------------
// final: reduce the 256 slots with one wave.
// ---------------------------------------------------------------------------
__global__ __launch_bounds__(64) void som_final_kernel(
    const float* __restrict__ slots, float* __restrict__ loss) {
  const int t = threadIdx.x;           // one wave
  float commit = 0.f, som = 0.f, cnt = 0.f;
#pragma unroll
  for (int i = 0; i < 4; ++i) {
    const float* sp = slots + (size_t)(i * 64 + t) * 16;
    commit += sp[0]; som += sp[1]; cnt += sp[2];
  }
  for (int off = 32; off > 0; off >>= 1) {
    commit += __shfl_down(commit, off, 64);
    som    += __shfl_down(som,    off, 64);
    cnt    += __shfl_down(cnt,    off, 64);
  }
  if (t == 0) loss[0] = 6.0f * (commit / COMMIT_DEN) + som / cnt;
}

extern "C" void kernel_launch(void* const* d_in, const int* in_sizes, int n_in,
                              void* d_out, int out_size, void* d_ws, size_t ws_size,
                              hipStream_t stream) {
  const float* x = (const float*)d_in[0];   // [8,32,32,32,32]
  const float* w = (const float*)d_in[1];   // [256,32]
  float* ws  = (float*)d_ws;                // NSLOT x 16 float slots
  float* o   = (float*)d_out;               // [0] loss, then out, then enc

  som_prep_kernel<<<1, 256, 0, stream>>>(ws);
  som_main_kernel<<<N_VOX / 256, 256, 0, stream>>>(
      x, w, ws, o + 1, o + 1 + OUT_ELEMS);
  som_final_kernel<<<1, 64, 0, stream>>>(ws, o);
}